// Round 5
// baseline (494.521 us; speedup 1.0000x reference)
//
#include <hip/hip_runtime.h>
#include <hip/hip_bf16.h>
#include <math.h>

typedef __bf16 bf16;
typedef __bf16 bf16x4 __attribute__((ext_vector_type(4)));
typedef __bf16 bf16x8 __attribute__((ext_vector_type(8)));
typedef float f32x4 __attribute__((ext_vector_type(4)));

#define GLB __attribute__((address_space(1)))
#define LDSAS __attribute__((address_space(3)))

// ---------------------------------------------------------------------------
// Dtype probe: flag=1 if d_in[0] is genuine fp32, 0 if packed bf16.
// ---------------------------------------------------------------------------
__global__ void probe_dtype(const unsigned int* __restrict__ X, int* __restrict__ flag) {
  int t = threadIdx.x;
  int cnt = 0;
  for (int i = t; i < 512; i += 64) {
    unsigned int e = (X[i] >> 7) & 0xFF;
    cnt += (e >= 110 && e <= 135) ? 1 : 0;
  }
#pragma unroll
  for (int off = 32; off > 0; off >>= 1) cnt += __shfl_down(cnt, off, 64);
  if (t == 0) flag[0] = (cnt < 256) ? 1 : 0;
}

// ---------------------------------------------------------------------------
// Prep v2: transpose+cast with 16B-coalesced writes (unchanged from round 2).
// ---------------------------------------------------------------------------
__global__ void prep_weights(const void* __restrict__ Wq, const void* __restrict__ Wk,
                             const void* __restrict__ Wv, const void* __restrict__ Wo,
                             const void* __restrict__ X,
                             bf16* __restrict__ Wqkvt, bf16* __restrict__ Wot,
                             bf16* __restrict__ Xb, const int* __restrict__ flag) {
  const int f = flag[0];
  const int t = threadIdx.x;  // 256 flat
  int b = blockIdx.x;
  __shared__ __attribute__((aligned(16))) bf16 tileT[64][72];
  const void* W;
  bf16* out;
  int N, bx, by;
  if (b < 4096) {                        // Wq [4096][4096]
    W = Wq; out = Wqkvt; N = 4096; bx = b & 63; by = b >> 6;
  } else if (b < 5120) {                 // Wk [4096][1024]
    b -= 4096; W = Wk; out = Wqkvt + (size_t)4096 * 4096; N = 1024; bx = b & 15; by = b >> 4;
  } else if (b < 6144) {                 // Wv [4096][1024]
    b -= 5120; W = Wv; out = Wqkvt + (size_t)5120 * 4096; N = 1024; bx = b & 15; by = b >> 4;
  } else if (b < 10240) {                // Wo [4096][4096]
    b -= 6144; W = Wo; out = Wot; N = 4096; bx = b & 63; by = b >> 6;
  } else {                               // X cast [2048][4096], 8192 blocks
    b -= 10240;
    const size_t i = ((size_t)b * 256 + t) * 4;
    bf16x4 o;
    if (f) {
      const float4 v = *(const float4*)((const float*)X + i);
      o[0] = (bf16)v.x; o[1] = (bf16)v.y; o[2] = (bf16)v.z; o[3] = (bf16)v.w;
    } else {
      o = *(const bf16x4*)((const bf16*)X + i);
    }
    *(bf16x4*)&Xb[i] = o;
    return;
  }
  const int n0 = bx * 64, k0 = by * 64;

  // ---- read in: 4 passes x 16 rows; lane covers 4 consecutive n
  const int rr = t >> 4, cc = (t & 15) * 4;
  const int s_in = (t & 15) >> 1;  // = ((cc+u)>>3)&7 for u<4
#pragma unroll
  for (int p = 0; p < 4; ++p) {
    const int r = p * 16 + rr;
    bf16 vals[4];
    if (f) {
      const float4 v = *(const float4*)((const float*)W + (size_t)(k0 + r) * N + n0 + cc);
      vals[0] = (bf16)v.x; vals[1] = (bf16)v.y; vals[2] = (bf16)v.z; vals[3] = (bf16)v.w;
    } else {
      const bf16x4 v = *(const bf16x4*)((const bf16*)W + (size_t)(k0 + r) * N + n0 + cc);
#pragma unroll
      for (int u = 0; u < 4; ++u) vals[u] = v[u];
    }
    const int idx = (((r >> 3) ^ s_in) << 3) + (r & 7);  // swizzled k-position
#pragma unroll
    for (int u = 0; u < 4; ++u) tileT[cc + u][idx] = vals[u];
  }
  __syncthreads();

  // ---- write out: 2 passes x 32 rows; one bf16x8 (16B) per lane per pass
  const int nn = t >> 3, c8 = t & 7;
#pragma unroll
  for (int p = 0; p < 2; ++p) {
    const int n = p * 32 + nn;
    const int s = (n >> 3) & 7;
    const bf16x8 v = *(const bf16x8*)&tileT[n][(c8 ^ s) * 8];
    *(bf16x8*)&out[(size_t)(n0 + n) * 4096 + k0 + c8 * 8] = v;
  }
}

// ---------------------------------------------------------------------------
// m97-style bf16 GEMM with XOR-swizzled LDS (harness-verified, ~833 TF).
// ---------------------------------------------------------------------------
__global__ __launch_bounds__(256, 2) void gemm_bt(
    const bf16* __restrict__ A, const bf16* __restrict__ Bt,
    void* __restrict__ C, const int* __restrict__ flagp, int M, int N, int K) {
  __shared__ bf16 As[128 * 32];
  __shared__ bf16 Bs[128 * 32];
  const int t = threadIdx.x;
  const int m0 = blockIdx.y * 128, n0 = blockIdx.x * 128;
  const int lane = t & 63, n16 = lane & 15, quad = lane >> 4;
  const int w = t >> 6, wrow = w >> 1, wcol = w & 1;

  f32x4 acc[4][4] = {};
  const int colA = (((t & 3) ^ ((t >> 3) & 3))) * 8;  // swizzled k-chunk
  const int rA = t >> 2;
  const int sw = (n16 >> 1) & 3;                       // read-side swizzle
  const int rdoff = ((quad ^ sw) * 8);

  for (int k0 = 0; k0 < K; k0 += 32) {
#pragma unroll
    for (int i = 0; i < 2; ++i) {
      const int elem = i * 2048 + t * 8;
      const int row = i * 64 + rA;
      __builtin_amdgcn_global_load_lds(
          (const GLB void*)(A + (size_t)(m0 + row) * K + k0 + colA),
          (LDSAS void*)(&As[elem]), 16, 0, 0);
      __builtin_amdgcn_global_load_lds(
          (const GLB void*)(Bt + (size_t)(n0 + row) * K + k0 + colA),
          (LDSAS void*)(&Bs[elem]), 16, 0, 0);
    }
    __syncthreads();
    bf16x8 af[4], bfr[4];
#pragma unroll
    for (int i = 0; i < 4; ++i) {
      af[i] = *(const bf16x8*)&As[(wrow * 64 + i * 16 + n16) * 32 + rdoff];
      bfr[i] = *(const bf16x8*)&Bs[(wcol * 64 + i * 16 + n16) * 32 + rdoff];
    }
#pragma unroll
    for (int mi = 0; mi < 4; ++mi)
#pragma unroll
      for (int ni = 0; ni < 4; ++ni)
        acc[mi][ni] = __builtin_amdgcn_mfma_f32_16x16x32_bf16(
            af[mi], bfr[ni], acc[mi][ni], 0, 0, 0);
    __syncthreads();
  }
  const bool f32out = (flagp != nullptr) && (flagp[0] != 0);
  if (f32out) {
    float* Cf = (float*)C;
#pragma unroll
    for (int mi = 0; mi < 4; ++mi)
#pragma unroll
      for (int ni = 0; ni < 4; ++ni) {
        const int r0 = m0 + wrow * 64 + mi * 16 + quad * 4;
        const int c = n0 + wcol * 64 + ni * 16 + n16;
#pragma unroll
        for (int r = 0; r < 4; ++r) Cf[(size_t)(r0 + r) * N + c] = acc[mi][ni][r];
      }
  } else {
    bf16* Cb = (bf16*)C;
#pragma unroll
    for (int mi = 0; mi < 4; ++mi)
#pragma unroll
      for (int ni = 0; ni < 4; ++ni) {
        const int r0 = m0 + wrow * 64 + mi * 16 + quad * 4;
        const int c = n0 + wcol * 64 + ni * 16 + n16;
#pragma unroll
        for (int r = 0; r < 4; ++r) Cb[(size_t)(r0 + r) * N + c] = (bf16)acc[mi][ni][r];
      }
  }
}

// ---------------------------------------------------------------------------
// RoPE v2 (sincos dedup) + V transpose.
//   Angle depends only on (s,i): compute sincos ONCE per (s,i) and loop the
//   40 heads (was 40x redundant sincosf = 5.24M -> 131K). Lanes cover i
//   consecutively -> 128B coalesced row segments per head.
//   Blocks 0..511: RoPE (2048 s x 64 i). Blocks 512..2559: V transpose.
// ---------------------------------------------------------------------------
__global__ void rope_vt(bf16* __restrict__ QKV, const int* __restrict__ pos,
                        bf16* __restrict__ Vt) {
  const int t = threadIdx.x;
  int b = blockIdx.x;
  if (b < 512) {
    const int i = t & 63;
    const int s = b * 4 + (t >> 6);
    const float p = (float)pos[s];
    const float inv = exp2f((float)i * -0.2076205088f);  // 10000^(-i/64)
    float sn, cs;
    sincosf(p * inv, &sn, &cs);
    bf16* base = QKV + (size_t)s * 6144 + i;
#pragma unroll 4
    for (int hh = 0; hh < 40; ++hh) {
      bf16* px = base + hh * 128;
      const float x1 = (float)px[0], x2 = (float)px[64];
      px[0] = (bf16)(x1 * cs - x2 * sn);
      px[64] = (bf16)(x2 * cs + x1 * sn);
    }
  } else {          // V transpose: [2048 s][1024 v] (stride 6144) -> Vt[v][s]
    b -= 512;
    __shared__ bf16 tile[32][34];
    const int tx = t & 31, ty = t >> 5;
    const int v0 = (b & 31) * 32, s0 = (b >> 5) * 32;
#pragma unroll
    for (int j = 0; j < 4; ++j)
      tile[ty + j * 8][tx] = QKV[(size_t)(s0 + ty + j * 8) * 6144 + 5120 + v0 + tx];
    __syncthreads();
#pragma unroll
    for (int j = 0; j < 4; ++j)
      Vt[(size_t)(v0 + ty + j * 8) * 2048 + s0 + tx] = tile[tx][ty + j * 8];
  }
}

// ---------------------------------------------------------------------------
// Flash attention v7: KVBLK=32 for 4 blocks/CU + XCD-aware head clustering.
//   LDS: Ks[2][32*128]=16K, Vs[2][128*32]=16K, Ps[64*48]=6K -> 38KB
//   => 4 blocks/CU (was 2 at 73.7KB): 16 waves/CU to hide barrier+L2 latency.
//   Grid remap: each XCD (flat&7) gets 4 consecutive h = one hkv K/V panel
//   (~1MB) -> L2-resident instead of 8MB thrash.
//   Swapped QK^T retained (lane: q=w*16+n16, kv=ns*16+quad*4+r, ns<2).
//   V rows now 64B (16 banks) -> PV B-reads bank-balanced with NO swizzle.
//   PV contraction = one 16x16x32 MFMA per dt (K=32).
//   Diag: the two tiles kt>=2*qt mask (dof + kvl > ql), dof = kt*32-qt*64.
// ---------------------------------------------------------------------------
__global__ __launch_bounds__(256, 4) void flash_attn(
    const bf16* __restrict__ QKV, const bf16* __restrict__ Vt_g,
    bf16* __restrict__ O) {
  __shared__ bf16 Ks[2][32 * 128];
  __shared__ bf16 Vs[2][128 * 32];
  __shared__ bf16 Ps[64 * 48];
  const int flat = blockIdx.y * 16 + blockIdx.x;
  const int m = flat >> 3;
  const int h = (flat & 7) * 4 + (m >> 4);   // XCD-clustered head
  const int pairp = m & 15;
  const int hkv = h >> 2;
  const int t = threadIdx.x, w = t >> 6, lane = t & 63;
  const int n16 = lane & 15, quad = lane >> 4;
  const bf16* Qp = QKV + h * 128;
  const bf16* Kp = QKV + 4096 + hkv * 128;
  const bf16* Vp = Vt_g + (size_t)hkv * 128 * 2048;

  const int krow = t >> 4, kg = t & 15;          // K staging: 16 rows/inst
  const int vd = t >> 2, vg = t & 3;             // V staging: 64 d-rows/inst

  for (int pass = 0; pass < 2; ++pass) {
    const int qt = (pass == 0) ? pairp : 31 - pairp;
    bf16x8 qa[4];
    {
      const bf16* qrow = Qp + (size_t)(qt * 64 + w * 16 + n16) * 6144 + quad * 8;
#pragma unroll
      for (int kf = 0; kf < 4; ++kf) qa[kf] = *(const bf16x8*)(qrow + kf * 32);
    }
    f32x4 o[8] = {};
    float l_ = 0.f;

    __syncthreads();  // protect buffers from previous pass readers

    auto stage = [&](int kt, int buf) {
#pragma unroll
      for (int j = 0; j < 2; ++j) {
        const int row = j * 16 + krow;
        const int g = kg ^ (row & 7);
        __builtin_amdgcn_global_load_lds(
            (const GLB void*)(Kp + (size_t)(kt * 32 + row) * 6144 + g * 8),
            (LDSAS void*)(&Ks[buf][j * 2048 + t * 8]), 16, 0, 0);
      }
#pragma unroll
      for (int j = 0; j < 2; ++j) {
        const int d = j * 64 + vd;
        __builtin_amdgcn_global_load_lds(
            (const GLB void*)(Vp + (size_t)d * 2048 + kt * 32 + vg * 8),
            (LDSAS void*)(&Vs[buf][j * 2048 + t * 8]), 16, 0, 0);
      }
    };

    const int nk = 2 * qt + 2;   // kv tiles of 32
    stage(0, 0);
    for (int kt = 0; kt < nk; ++kt) {
      const int cur = kt & 1;
      __syncthreads();                    // drains cur's loads
      if (kt + 1 < nk) stage(kt + 1, cur ^ 1);

      // ---- S^T = (K Q^T)/sqrt(D); lane: q = w*16+n16, kv = ns*16+quad*4+r
      const bool diag = (kt >= 2 * qt);
      const int dof = kt * 32 - qt * 64;  // 0 or 32 on diag tiles
      const int s7 = n16 & 7;
      const int qloc = w * 16 + n16;
#pragma unroll
      for (int ns = 0; ns < 2; ++ns) {
        f32x4 c = {};
        __builtin_amdgcn_s_setprio(1);
#pragma unroll
        for (int kf = 0; kf < 4; ++kf)
          c = __builtin_amdgcn_mfma_f32_16x16x32_bf16(
              *(const bf16x8*)&Ks[cur][(ns * 16 + n16) * 128 +
                                       (((kf * 4 + quad) ^ s7) * 8)],
              qa[kf], c, 0, 0, 0);
        __builtin_amdgcn_s_setprio(0);
        float p[4];
        if (diag) {
          const int kv0 = dof + ns * 16 + quad * 4;
#pragma unroll
          for (int r = 0; r < 4; ++r)
            p[r] = (kv0 + r > qloc)
                       ? 0.f
                       : __expf(fminf(c[r] * 0.08838834764831845f, 60.f));
        } else {
#pragma unroll
          for (int r = 0; r < 4; ++r)
            p[r] = __expf(fminf(c[r] * 0.08838834764831845f, 60.f));
        }
        l_ += (p[0] + p[1]) + (p[2] + p[3]);
        bf16x4 pb;
#pragma unroll
        for (int r = 0; r < 4; ++r) pb[r] = (bf16)p[r];
        *(bf16x4*)&Ps[(size_t)qloc * 48 + ns * 16 + quad * 4] = pb;
      }
      // ---- O += P V (one MFMA per dt, K=32)
      const bf16x8 a0 = *(const bf16x8*)&Ps[(w * 16 + n16) * 48 + quad * 8];
      __builtin_amdgcn_s_setprio(1);
#pragma unroll
      for (int dt = 0; dt < 8; ++dt) {
        const int d = dt * 16 + n16;
        const bf16x8 b0 = *(const bf16x8*)&Vs[cur][d * 32 + quad * 8];
        o[dt] = __builtin_amdgcn_mfma_f32_16x16x32_bf16(a0, b0, o[dt], 0, 0, 0);
      }
      __builtin_amdgcn_s_setprio(0);
    }
    // ---- l: reduce across quads (lanes with same n16 hold same q)
    l_ += __shfl_xor(l_, 16, 64);
    l_ += __shfl_xor(l_, 32, 64);
    float linv[4];
#pragma unroll
    for (int r = 0; r < 4; ++r) linv[r] = 1.f / __shfl(l_, quad * 4 + r, 64);
#pragma unroll
    for (int dt = 0; dt < 8; ++dt)
#pragma unroll
      for (int r = 0; r < 4; ++r) {
        const int qi = qt * 64 + w * 16 + quad * 4 + r;
        O[(size_t)qi * 4096 + h * 128 + dt * 16 + n16] = (bf16)(o[dt][r] * linv[r]);
      }
  }
}

// ---------------------------------------------------------------------------
extern "C" void kernel_launch(void* const* d_in, const int* in_sizes, int n_in,
                              void* d_out, int out_size, void* d_ws, size_t ws_size,
                              hipStream_t stream) {
  (void)in_sizes; (void)n_in; (void)out_size; (void)ws_size;
  const void* X = d_in[0];
  const int* pos = (const int*)d_in[1];
  const void* Wq = d_in[2];
  const void* Wk = d_in[3];
  const void* Wv = d_in[4];
  const void* Wo = d_in[5];

  char* ws = (char*)d_ws;
  const size_t MB = 1ull << 20;
  int* flag   = (int*)(ws + 0);
  bf16* Xb    = (bf16*)(ws + 1 * MB);    // 16 MiB (aliased by attn later)
  bf16* attn  = (bf16*)(ws + 1 * MB);    // alias: Xb dead after QKV GEMM
  bf16* Wqkvt = (bf16*)(ws + 17 * MB);   // [6144][4096] = 48 MiB
  bf16* Wot   = (bf16*)(ws + 65 * MB);   // 32 MiB
  bf16* QKV   = (bf16*)(ws + 97 * MB);   // [2048][6144] = 24 MiB
  bf16* Vt_g  = (bf16*)(ws + 121 * MB);  // [1024][2048] = 4 MiB -> 125 MiB

  probe_dtype<<<1, 64, 0, stream>>>((const unsigned int*)X, flag);

  // 10240 transpose blocks (64x64 tiles) + 8192 X-cast blocks
  prep_weights<<<18432, 256, 0, stream>>>(Wq, Wk, Wv, Wo, X, Wqkvt, Wot, Xb, flag);

  // fused QKV projection: [2048][4096] @ [4096][6144]^T-stored -> [2048][6144]
  gemm_bt<<<dim3(48, 16), 256, 0, stream>>>(Xb, Wqkvt, QKV, nullptr, 2048, 6144, 4096);

  rope_vt<<<2560, 256, 0, stream>>>(QKV, pos, Vt_g);  // RoPE(Q,K) + V^T

  flash_attn<<<dim3(16, 32), 256, 0, stream>>>(QKV, Vt_g, attn);

  gemm_bt<<<dim3(32, 16), 256, 0, stream>>>(attn, Wot, d_out, flag, 2048, 4096, 4096);
}

// Round 6
// 475.177 us; speedup vs baseline: 1.0407x; 1.0407x over previous
//
#include <hip/hip_runtime.h>
#include <hip/hip_bf16.h>
#include <math.h>

typedef __bf16 bf16;
typedef __bf16 bf16x4 __attribute__((ext_vector_type(4)));
typedef __bf16 bf16x8 __attribute__((ext_vector_type(8)));
typedef float f32x4 __attribute__((ext_vector_type(4)));

#define GLB __attribute__((address_space(1)))
#define LDSAS __attribute__((address_space(3)))

// ---------------------------------------------------------------------------
// Dtype probe: flag=1 if d_in[0] is genuine fp32, 0 if packed bf16.
// ---------------------------------------------------------------------------
__global__ void probe_dtype(const unsigned int* __restrict__ X, int* __restrict__ flag) {
  int t = threadIdx.x;
  int cnt = 0;
  for (int i = t; i < 512; i += 64) {
    unsigned int e = (X[i] >> 7) & 0xFF;
    cnt += (e >= 110 && e <= 135) ? 1 : 0;
  }
#pragma unroll
  for (int off = 32; off > 0; off >>= 1) cnt += __shfl_down(cnt, off, 64);
  if (t == 0) flag[0] = (cnt < 256) ? 1 : 0;
}

// ---------------------------------------------------------------------------
// Prep v2: transpose+cast with 16B-coalesced writes (unchanged from round 2).
// ---------------------------------------------------------------------------
__global__ void prep_weights(const void* __restrict__ Wq, const void* __restrict__ Wk,
                             const void* __restrict__ Wv, const void* __restrict__ Wo,
                             const void* __restrict__ X,
                             bf16* __restrict__ Wqkvt, bf16* __restrict__ Wot,
                             bf16* __restrict__ Xb, const int* __restrict__ flag) {
  const int f = flag[0];
  const int t = threadIdx.x;  // 256 flat
  int b = blockIdx.x;
  __shared__ __attribute__((aligned(16))) bf16 tileT[64][72];
  const void* W;
  bf16* out;
  int N, bx, by;
  if (b < 4096) {                        // Wq [4096][4096]
    W = Wq; out = Wqkvt; N = 4096; bx = b & 63; by = b >> 6;
  } else if (b < 5120) {                 // Wk [4096][1024]
    b -= 4096; W = Wk; out = Wqkvt + (size_t)4096 * 4096; N = 1024; bx = b & 15; by = b >> 4;
  } else if (b < 6144) {                 // Wv [4096][1024]
    b -= 5120; W = Wv; out = Wqkvt + (size_t)5120 * 4096; N = 1024; bx = b & 15; by = b >> 4;
  } else if (b < 10240) {                // Wo [4096][4096]
    b -= 6144; W = Wo; out = Wot; N = 4096; bx = b & 63; by = b >> 6;
  } else {                               // X cast [2048][4096], 8192 blocks
    b -= 10240;
    const size_t i = ((size_t)b * 256 + t) * 4;
    bf16x4 o;
    if (f) {
      const float4 v = *(const float4*)((const float*)X + i);
      o[0] = (bf16)v.x; o[1] = (bf16)v.y; o[2] = (bf16)v.z; o[3] = (bf16)v.w;
    } else {
      o = *(const bf16x4*)((const bf16*)X + i);
    }
    *(bf16x4*)&Xb[i] = o;
    return;
  }
  const int n0 = bx * 64, k0 = by * 64;

  // ---- read in: 4 passes x 16 rows; lane covers 4 consecutive n
  const int rr = t >> 4, cc = (t & 15) * 4;
  const int s_in = (t & 15) >> 1;  // = ((cc+u)>>3)&7 for u<4
#pragma unroll
  for (int p = 0; p < 4; ++p) {
    const int r = p * 16 + rr;
    bf16 vals[4];
    if (f) {
      const float4 v = *(const float4*)((const float*)W + (size_t)(k0 + r) * N + n0 + cc);
      vals[0] = (bf16)v.x; vals[1] = (bf16)v.y; vals[2] = (bf16)v.z; vals[3] = (bf16)v.w;
    } else {
      const bf16x4 v = *(const bf16x4*)((const bf16*)W + (size_t)(k0 + r) * N + n0 + cc);
#pragma unroll
      for (int u = 0; u < 4; ++u) vals[u] = v[u];
    }
    const int idx = (((r >> 3) ^ s_in) << 3) + (r & 7);  // swizzled k-position
#pragma unroll
    for (int u = 0; u < 4; ++u) tileT[cc + u][idx] = vals[u];
  }
  __syncthreads();

  // ---- write out: 2 passes x 32 rows; one bf16x8 (16B) per lane per pass
  const int nn = t >> 3, c8 = t & 7;
#pragma unroll
  for (int p = 0; p < 2; ++p) {
    const int n = p * 32 + nn;
    const int s = (n >> 3) & 7;
    const bf16x8 v = *(const bf16x8*)&tileT[n][(c8 ^ s) * 8];
    *(bf16x8*)&out[(size_t)(n0 + n) * 4096 + k0 + c8 * 8] = v;
  }
}

// ---------------------------------------------------------------------------
// gemm_bt v2: m97 structure with BK=64 (was 32).
//   LDS 2x128x64x2B = 32KB -> residency stays ~3 blocks/CU (m132's BK=128
//   regression was the 64KB->2 blocks cliff; 32KB avoids it). Half the
//   barrier/vmcnt drains per K. K-summation order preserved (kk=0 then 1,
//   ascending k) -> bit-identical accumulation vs BK=32.
//   Swizzle: 8 chunks/row; src chunk (t&7)^(row&7), linear LDS dest (rule 21),
//   read phys chunk (kk*4+quad)^(row&7). Quarter-wave bank check: byte =
//   row*128 + chunk*16 -> dword-bank 4*chunk mod 32 (row term vanishes),
//   16 lanes cover 8 chunks x2 = 2 lanes/bank-group = conflict-free.
// ---------------------------------------------------------------------------
__global__ __launch_bounds__(256, 2) void gemm_bt(
    const bf16* __restrict__ A, const bf16* __restrict__ Bt,
    void* __restrict__ C, const int* __restrict__ flagp, int M, int N, int K) {
  __shared__ bf16 As[128 * 64];
  __shared__ bf16 Bs[128 * 64];
  const int t = threadIdx.x;
  const int m0 = blockIdx.y * 128, n0 = blockIdx.x * 128;
  const int lane = t & 63, n16 = lane & 15, quad = lane >> 4;
  const int w = t >> 6, wrow = w >> 1, wcol = w & 1;

  f32x4 acc[4][4] = {};
  const int rA = t >> 3;                      // row within each 32-row group
  const int colA = ((t & 7) ^ (rA & 7)) * 8;  // pre-swizzled source k-chunk

  for (int k0 = 0; k0 < K; k0 += 64) {
#pragma unroll
    for (int i = 0; i < 4; ++i) {
      const int elem = i * 2048 + t * 8;
      const int row = i * 32 + rA;
      __builtin_amdgcn_global_load_lds(
          (const GLB void*)(A + (size_t)(m0 + row) * K + k0 + colA),
          (LDSAS void*)(&As[elem]), 16, 0, 0);
      __builtin_amdgcn_global_load_lds(
          (const GLB void*)(Bt + (size_t)(n0 + row) * K + k0 + colA),
          (LDSAS void*)(&Bs[elem]), 16, 0, 0);
    }
    __syncthreads();
#pragma unroll
    for (int kk = 0; kk < 2; ++kk) {
      bf16x8 af[4], bfr[4];
#pragma unroll
      for (int i = 0; i < 4; ++i) {
        const int rowa = wrow * 64 + i * 16 + n16;
        af[i] = *(const bf16x8*)&As[rowa * 64 + (((kk * 4 + quad) ^ (rowa & 7)) * 8)];
        const int rowb = wcol * 64 + i * 16 + n16;
        bfr[i] = *(const bf16x8*)&Bs[rowb * 64 + (((kk * 4 + quad) ^ (rowb & 7)) * 8)];
      }
#pragma unroll
      for (int mi = 0; mi < 4; ++mi)
#pragma unroll
        for (int ni = 0; ni < 4; ++ni)
          acc[mi][ni] = __builtin_amdgcn_mfma_f32_16x16x32_bf16(
              af[mi], bfr[ni], acc[mi][ni], 0, 0, 0);
    }
    __syncthreads();
  }
  const bool f32out = (flagp != nullptr) && (flagp[0] != 0);
  if (f32out) {
    float* Cf = (float*)C;
#pragma unroll
    for (int mi = 0; mi < 4; ++mi)
#pragma unroll
      for (int ni = 0; ni < 4; ++ni) {
        const int r0 = m0 + wrow * 64 + mi * 16 + quad * 4;
        const int c = n0 + wcol * 64 + ni * 16 + n16;
#pragma unroll
        for (int r = 0; r < 4; ++r) Cf[(size_t)(r0 + r) * N + c] = acc[mi][ni][r];
      }
  } else {
    bf16* Cb = (bf16*)C;
#pragma unroll
    for (int mi = 0; mi < 4; ++mi)
#pragma unroll
      for (int ni = 0; ni < 4; ++ni) {
        const int r0 = m0 + wrow * 64 + mi * 16 + quad * 4;
        const int c = n0 + wcol * 64 + ni * 16 + n16;
#pragma unroll
        for (int r = 0; r < 4; ++r) Cb[(size_t)(r0 + r) * N + c] = (bf16)acc[mi][ni][r];
      }
  }
}

// ---------------------------------------------------------------------------
// RoPE v2 (sincos dedup) + V transpose (kept from round 5).
// ---------------------------------------------------------------------------
__global__ void rope_vt(bf16* __restrict__ QKV, const int* __restrict__ pos,
                        bf16* __restrict__ Vt) {
  const int t = threadIdx.x;
  int b = blockIdx.x;
  if (b < 512) {
    const int i = t & 63;
    const int s = b * 4 + (t >> 6);
    const float p = (float)pos[s];
    const float inv = exp2f((float)i * -0.2076205088f);  // 10000^(-i/64)
    float sn, cs;
    sincosf(p * inv, &sn, &cs);
    bf16* base = QKV + (size_t)s * 6144 + i;
#pragma unroll 4
    for (int hh = 0; hh < 40; ++hh) {
      bf16* px = base + hh * 128;
      const float x1 = (float)px[0], x2 = (float)px[64];
      px[0] = (bf16)(x1 * cs - x2 * sn);
      px[64] = (bf16)(x2 * cs + x1 * sn);
    }
  } else {          // V transpose: [2048 s][1024 v] (stride 6144) -> Vt[v][s]
    b -= 512;
    __shared__ bf16 tile[32][34];
    const int tx = t & 31, ty = t >> 5;
    const int v0 = (b & 31) * 32, s0 = (b >> 5) * 32;
#pragma unroll
    for (int j = 0; j < 4; ++j)
      tile[ty + j * 8][tx] = QKV[(size_t)(s0 + ty + j * 8) * 6144 + 5120 + v0 + tx];
    __syncthreads();
#pragma unroll
    for (int j = 0; j < 4; ++j)
      Vt[(size_t)(v0 + ty + j * 8) * 2048 + s0 + tx] = tile[tx][ty + j * 8];
  }
}

// ---------------------------------------------------------------------------
// Flash attention v6 (round-3 verified version, reverted from v7):
//   KVBLK=64, swapped QK^T (lane: q=w*16+n16, kv=ns*16+quad*4+r).
//   v7 (KVBLK=32) was neutral-to-negative: grid is 512 blocks = 2/CU, so the
//   4-blocks/CU LDS headroom never materialized and barrier count doubled.
// ---------------------------------------------------------------------------
__global__ __launch_bounds__(256) void flash_attn(
    const bf16* __restrict__ QKV, const bf16* __restrict__ Vt_g,
    bf16* __restrict__ O) {
  __shared__ bf16 Ks[2][64 * 128];
  __shared__ bf16 Vs[2][128 * 64];
  __shared__ bf16 Ps[64 * 72];
  const int pairp = blockIdx.x;
  const int h = blockIdx.y, hkv = h >> 2;
  const int t = threadIdx.x, w = t >> 6, lane = t & 63;
  const int n16 = lane & 15, quad = lane >> 4;
  const bf16* Qp = QKV + h * 128;
  const bf16* Kp = QKV + 4096 + hkv * 128;
  const bf16* Vp = Vt_g + (size_t)hkv * 128 * 2048;

  const int krow = t >> 4, kg = t & 15;
  const int vd = t >> 3, vg = t & 7;

  for (int pass = 0; pass < 2; ++pass) {
    const int qt = (pass == 0) ? pairp : 31 - pairp;
    bf16x8 qa[4];
    {
      const bf16* qrow = Qp + (size_t)(qt * 64 + w * 16 + n16) * 6144 + quad * 8;
#pragma unroll
      for (int kf = 0; kf < 4; ++kf) qa[kf] = *(const bf16x8*)(qrow + kf * 32);
    }
    f32x4 o[8] = {};
    float l_ = 0.f;

    __syncthreads();  // protect buffers from previous pass readers

    auto stage = [&](int kt, int buf) {
#pragma unroll
      for (int j = 0; j < 4; ++j) {
        const int row = j * 16 + krow;
        const int g = kg ^ (row & 7);
        __builtin_amdgcn_global_load_lds(
            (const GLB void*)(Kp + (size_t)(kt * 64 + row) * 6144 + g * 8),
            (LDSAS void*)(&Ks[buf][j * 2048 + t * 8]), 16, 0, 0);
      }
#pragma unroll
      for (int j = 0; j < 4; ++j) {
        const int d = j * 32 + vd;
        const int g = vg ^ (d & 7);
        __builtin_amdgcn_global_load_lds(
            (const GLB void*)(Vp + (size_t)d * 2048 + kt * 64 + g * 8),
            (LDSAS void*)(&Vs[buf][j * 2048 + t * 8]), 16, 0, 0);
      }
    };

    stage(0, 0);
    for (int kt = 0; kt <= qt; ++kt) {
      const int cur = kt & 1;
      __syncthreads();                    // drains cur's loads
      if (kt < qt) stage(kt + 1, cur ^ 1);

      // ---- S^T = (K Q^T)/sqrt(D); lane: q = w*16+n16, kv = ns*16+quad*4+r
      const bool diag = (kt == qt);
      const int s7 = n16 & 7;
      const int qloc = w * 16 + n16;
#pragma unroll
      for (int ns = 0; ns < 4; ++ns) {
        f32x4 c = {};
        __builtin_amdgcn_s_setprio(1);
#pragma unroll
        for (int kf = 0; kf < 4; ++kf)
          c = __builtin_amdgcn_mfma_f32_16x16x32_bf16(
              *(const bf16x8*)&Ks[cur][(ns * 16 + n16) * 128 +
                                       (((kf * 4 + quad) ^ s7) * 8)],
              qa[kf], c, 0, 0, 0);
        __builtin_amdgcn_s_setprio(0);
        float p[4];
        if (diag) {
          const int kv0 = ns * 16 + quad * 4;
#pragma unroll
          for (int r = 0; r < 4; ++r)
            p[r] = (kv0 + r > qloc)
                       ? 0.f
                       : __expf(fminf(c[r] * 0.08838834764831845f, 60.f));
        } else {
#pragma unroll
          for (int r = 0; r < 4; ++r)
            p[r] = __expf(fminf(c[r] * 0.08838834764831845f, 60.f));
        }
        l_ += (p[0] + p[1]) + (p[2] + p[3]);
        bf16x4 pb;
#pragma unroll
        for (int r = 0; r < 4; ++r) pb[r] = (bf16)p[r];
        *(bf16x4*)&Ps[(size_t)qloc * 72 + ns * 16 + quad * 4] = pb;
      }
      // ---- O += P V (A-frag layout matches Ps rows)
      const bf16x8 a0 = *(const bf16x8*)&Ps[(w * 16 + n16) * 72 + quad * 8];
      const bf16x8 a1 = *(const bf16x8*)&Ps[(w * 16 + n16) * 72 + 32 + quad * 8];
      __builtin_amdgcn_s_setprio(1);
#pragma unroll
      for (int dt = 0; dt < 8; ++dt) {
        const int d = dt * 16 + n16;
        const bf16x8 b0 = *(const bf16x8*)&Vs[cur][d * 64 + ((quad ^ s7) * 8)];
        o[dt] = __builtin_amdgcn_mfma_f32_16x16x32_bf16(a0, b0, o[dt], 0, 0, 0);
        const bf16x8 b1 = *(const bf16x8*)&Vs[cur][d * 64 + (((4 + quad) ^ s7) * 8)];
        o[dt] = __builtin_amdgcn_mfma_f32_16x16x32_bf16(a1, b1, o[dt], 0, 0, 0);
      }
      __builtin_amdgcn_s_setprio(0);
    }
    // ---- l: reduce across quads (lanes with same n16 hold same q)
    l_ += __shfl_xor(l_, 16, 64);
    l_ += __shfl_xor(l_, 32, 64);
    float linv[4];
#pragma unroll
    for (int r = 0; r < 4; ++r) linv[r] = 1.f / __shfl(l_, quad * 4 + r, 64);
#pragma unroll
    for (int dt = 0; dt < 8; ++dt)
#pragma unroll
      for (int r = 0; r < 4; ++r) {
        const int qi = qt * 64 + w * 16 + quad * 4 + r;
        O[(size_t)qi * 4096 + h * 128 + dt * 16 + n16] = (bf16)(o[dt][r] * linv[r]);
      }
  }
}

// ---------------------------------------------------------------------------
extern "C" void kernel_launch(void* const* d_in, const int* in_sizes, int n_in,
                              void* d_out, int out_size, void* d_ws, size_t ws_size,
                              hipStream_t stream) {
  (void)in_sizes; (void)n_in; (void)out_size; (void)ws_size;
  const void* X = d_in[0];
  const int* pos = (const int*)d_in[1];
  const void* Wq = d_in[2];
  const void* Wk = d_in[3];
  const void* Wv = d_in[4];
  const void* Wo = d_in[5];

  char* ws = (char*)d_ws;
  const size_t MB = 1ull << 20;
  int* flag   = (int*)(ws + 0);
  bf16* Xb    = (bf16*)(ws + 1 * MB);    // 16 MiB (aliased by attn later)
  bf16* attn  = (bf16*)(ws + 1 * MB);    // alias: Xb dead after QKV GEMM
  bf16* Wqkvt = (bf16*)(ws + 17 * MB);   // [6144][4096] = 48 MiB
  bf16* Wot   = (bf16*)(ws + 65 * MB);   // 32 MiB
  bf16* QKV   = (bf16*)(ws + 97 * MB);   // [2048][6144] = 24 MiB
  bf16* Vt_g  = (bf16*)(ws + 121 * MB);  // [1024][2048] = 4 MiB -> 125 MiB

  probe_dtype<<<1, 64, 0, stream>>>((const unsigned int*)X, flag);

  // 10240 transpose blocks (64x64 tiles) + 8192 X-cast blocks
  prep_weights<<<18432, 256, 0, stream>>>(Wq, Wk, Wv, Wo, X, Wqkvt, Wot, Xb, flag);

  // fused QKV projection: [2048][4096] @ [4096][6144]^T-stored -> [2048][6144]
  gemm_bt<<<dim3(48, 16), 256, 0, stream>>>(Xb, Wqkvt, QKV, nullptr, 2048, 6144, 4096);

  rope_vt<<<2560, 256, 0, stream>>>(QKV, pos, Vt_g);  // RoPE(Q,K) + V^T

  flash_attn<<<dim3(16, 32), 256, 0, stream>>>(QKV, Vt_g, attn);

  gemm_bt<<<dim3(32, 16), 256, 0, stream>>>(attn, Wot, d_out, flag, 2048, 4096, 4096);
}